// Round 5
// baseline (98.568 us; speedup 1.0000x reference)
//
#include <hip/hip_runtime.h>
#include <math.h>

#define BB 4
#define NN 2048
#define CIN 64
#define HID 128
#define HEADS 4
#define DD 32
#define NQ 16
#define KTOT (NN*HID) // 262144
#define LOG2E 1.44269504088896340736f
#define NEGBIG -100.0f

typedef __attribute__((ext_vector_type(8))) _Float16 half8;
typedef __attribute__((ext_vector_type(4))) _Float16 half4;
typedef __attribute__((ext_vector_type(2))) _Float16 half2;
typedef __attribute__((ext_vector_type(4))) float f32x4;

// ---------------- Kernel A: h = x@W_in + b (f16 out), alpha_src/dst (pre-scaled by log2e) ----
__global__ __launch_bounds__(256) void k_hidden(
    const float* __restrict__ x, const float* __restrict__ W_in,
    const float* __restrict__ b_in, const float* __restrict__ att_src,
    const float* __restrict__ att_dst, _Float16* __restrict__ hH,
    float* __restrict__ srcA, float* __restrict__ dstA)
{
    __shared__ float Wl[CIN * HID];   // 32 KB
    __shared__ float xl[16][CIN];     // 4 KB
    const int t = threadIdx.x;
    const int jj0 = blockIdx.x * 16;

    {
        const float4* Ws = (const float4*)W_in;
        float4* Wd = (float4*)Wl;
#pragma unroll
        for (int u = 0; u < 8; ++u) Wd[t + 256 * u] = Ws[t + 256 * u];
        ((float4*)&xl[0][0])[t] = ((const float4*)(x + (size_t)jj0 * CIN))[t];
    }
    __syncthreads();

    const int c = t & 127, rg = t >> 7;
    const int b = jj0 >> 11, j0 = jj0 & (NN - 1);
    const int h = c >> 5;

    float acc[8];
    const float bc = b_in[c];
#pragma unroll
    for (int rr = 0; rr < 8; ++rr) acc[rr] = bc;

#pragma unroll
    for (int k4 = 0; k4 < CIN; k4 += 4) {
        const float w0 = Wl[(k4 + 0) * HID + c];
        const float w1 = Wl[(k4 + 1) * HID + c];
        const float w2 = Wl[(k4 + 2) * HID + c];
        const float w3 = Wl[(k4 + 3) * HID + c];
#pragma unroll
        for (int rr = 0; rr < 8; ++rr) {
            const float4 xv = *(const float4*)&xl[rg * 8 + rr][k4];
            acc[rr] = fmaf(xv.w, w3, fmaf(xv.z, w2, fmaf(xv.y, w1, fmaf(xv.x, w0, acc[rr]))));
        }
    }

    half8 hv;
#pragma unroll
    for (int rr = 0; rr < 8; ++rr) hv[rr] = (_Float16)acc[rr];
    *(half8*)(hH + (size_t)(b * HID + c) * NN + j0 + rg * 8) = hv;

    const float as = att_src[c], ad = att_dst[c];
#pragma unroll
    for (int rr = 0; rr < 8; ++rr) {
        float vs = acc[rr] * as, vd = acc[rr] * ad;
#pragma unroll
        for (int m = 16; m >= 1; m >>= 1) {
            vs += __shfl_xor(vs, m, 64);
            vd += __shfl_xor(vd, m, 64);
        }
        if ((t & 31) == 0) {
            srcA[(size_t)(b * HEADS + h) * NN + j0 + rg * 8 + rr] = vs * LOG2E;
            dstA[(size_t)(b * HEADS + h) * NN + j0 + rg * 8 + rr] = vd * LOG2E;
        }
    }
}

// ---------------- k_adjb: adj -> bitmask; block 0 also inits d_out with bias ----------------
__global__ __launch_bounds__(256) void k_adjb(const int* __restrict__ adj,
                                              unsigned* __restrict__ adjb,
                                              const float* __restrict__ b_out,
                                              float* __restrict__ dout)
{
    if (blockIdx.x == 0 && threadIdx.x < 64) dout[threadIdx.x] = b_out[threadIdx.x & 15];
    const int wid = blockIdx.x * 4 + (threadIdx.x >> 6);
    const int lane = threadIdx.x & 63;
    const int i = wid >> 5;            // row
    const int jc = wid & 31;           // 64-col chunk
    const int a = adj[(size_t)i * NN + jc * 64 + lane];
    const unsigned long long m = __ballot(a != 0);
    if (lane == 0) {
        *(uint2*)(adjb + (size_t)i * (NN / 32) + jc * 2) =
            make_uint2((unsigned)m, (unsigned)(m >> 32));
    }
}

// ---------------- Kernel B: MFMA flash-GAT, j-split partials ----------------
// grid 1024 = (jh, b, 16-row i-tile); 8 waves = 4 heads x 2 j-quarters (512 j each)
__global__ __launch_bounds__(512, 8) void k_attn(
    const unsigned* __restrict__ adjb, const _Float16* __restrict__ hH,
    const float* __restrict__ srcA, const float* __restrict__ dstA,
    _Float16* __restrict__ P, float* __restrict__ S)
{
    __shared__ float redA[8][16][36];       // 18.4 KB
    __shared__ float redS[8][16];           // 512 B

    const int t = threadIdx.x;
    const int lane = t & 63;
    const int w = t >> 6;
    const int h = w & 3;
    const int bx = blockIdx.x;
    const int jh = bx >> 9;
    const int b = (bx >> 7) & 3;
    const int i0 = (bx & 127) * 16;
    const int jstart = jh * 1024 + (w >> 2) * 512;

    const int r16 = lane & 15;
    const int g = lane >> 4;
    const float srci = srcA[(size_t)(b * HEADS + h) * NN + i0 + r16];
    const uint2* adjrow2 = (const uint2*)(adjb + (size_t)(i0 + r16) * (NN / 32)) + (jstart >> 6);
    const _Float16* bbase = hH + ((size_t)(b * HID) + h * DD + r16) * NN + jstart + 8 * g;
    const float4* dst4 = (const float4*)(dstA + (size_t)(b * HEADS + h) * NN + jstart) + 2 * g;

    f32x4 acc0 = {0.f, 0.f, 0.f, 0.f};
    f32x4 acc1 = {0.f, 0.f, 0.f, 0.f};
    f32x4 accS = {0.f, 0.f, 0.f, 0.f};
    const half8 ones = {(_Float16)1.f, (_Float16)1.f, (_Float16)1.f, (_Float16)1.f,
                        (_Float16)1.f, (_Float16)1.f, (_Float16)1.f, (_Float16)1.f};

    for (int it = 0; it < 8; ++it) {
        const uint2 aw2 = adjrow2[it];
        const half8 b0a = *(const half8*)(bbase + it * 64);
        const half8 b0b = *(const half8*)(bbase + it * 64 + 32);
        const half8 b1a = *(const half8*)(bbase + 16 * NN + it * 64);
        const half8 b1b = *(const half8*)(bbase + 16 * NN + it * 64 + 32);
        const float4 d0a = dst4[it * 16];
        const float4 d0b = dst4[it * 16 + 1];
        const float4 d1a = dst4[it * 16 + 8];
        const float4 d1b = dst4[it * 16 + 9];

#pragma unroll
        for (int s2 = 0; s2 < 2; ++s2) {
            const unsigned bits = (s2 ? aw2.y : aw2.x) >> (8 * g);
            const float4 da = s2 ? d1a : d0a;
            const float4 db = s2 ? d1b : d0b;
            const float dv[8] = {da.x, da.y, da.z, da.w, db.x, db.y, db.z, db.w};
            float wv[8];
#pragma unroll
            for (int e = 0; e < 8; ++e) {
                float s = srci + dv[e];
                s = fmaxf(s, 0.2f * s);                    // leaky relu (scaled)
                s = (bits & (1u << e)) ? s : NEGBIG;       // mask -> exp2 ~ 0
                wv[e] = __builtin_amdgcn_exp2f(s);
            }
            const half2 p0 = __builtin_bit_cast(half2, __builtin_amdgcn_cvt_pkrtz(wv[0], wv[1]));
            const half2 p1 = __builtin_bit_cast(half2, __builtin_amdgcn_cvt_pkrtz(wv[2], wv[3]));
            const half2 p2 = __builtin_bit_cast(half2, __builtin_amdgcn_cvt_pkrtz(wv[4], wv[5]));
            const half2 p3 = __builtin_bit_cast(half2, __builtin_amdgcn_cvt_pkrtz(wv[6], wv[7]));
            half8 af;
            af[0] = p0[0]; af[1] = p0[1]; af[2] = p1[0]; af[3] = p1[1];
            af[4] = p2[0]; af[5] = p2[1]; af[6] = p3[0]; af[7] = p3[1];
            const half8 bb0 = s2 ? b0b : b0a;
            const half8 bb1 = s2 ? b1b : b1a;
            acc0 = __builtin_amdgcn_mfma_f32_16x16x32_f16(af, bb0, acc0, 0, 0, 0);
            acc1 = __builtin_amdgcn_mfma_f32_16x16x32_f16(af, bb1, acc1, 0, 0, 0);
            accS = __builtin_amdgcn_mfma_f32_16x16x32_f16(af, ones, accS, 0, 0, 0);
        }
    }

    // C layout: col=lane&15 (=i within tile... here col=r16 -> i? no: col = output col = i-row index)
    // mfma(K=af rows... ) -- same mapping as previous rounds (verified): row=4*g+r over d, col=r16 over i.
#pragma unroll
    for (int r = 0; r < 4; ++r) {
        redA[w][4 * g + r][r16]      = acc0[r];
        redA[w][4 * g + r][16 + r16] = acc1[r];
    }
    if (r16 == 0) {
#pragma unroll
        for (int r = 0; r < 4; ++r) redS[w][4 * g + r] = accS[r];
    }
    __syncthreads();

    // combine the two j-quarters, pack f16, store partials
    {
        const int i = t >> 5;
        const int q = t & 31;
        const int h2 = q >> 3;
        const int d0 = (q & 7) * 4;
        const float4 v0 = *(const float4*)&redA[h2][i][d0];
        const float4 v1 = *(const float4*)&redA[h2 + 4][i][d0];
        const half2 lo = __builtin_bit_cast(half2, __builtin_amdgcn_cvt_pkrtz(v0.x + v1.x, v0.y + v1.y));
        const half2 hi = __builtin_bit_cast(half2, __builtin_amdgcn_cvt_pkrtz(v0.z + v1.z, v0.w + v1.w));
        half4 o; o[0] = lo[0]; o[1] = lo[1]; o[2] = hi[0]; o[3] = hi[1];
        *(half4*)(P + ((size_t)(jh * BB + b) * NN + i0 + i) * HID + h2 * DD + d0) = o;
        if ((q & 7) == 0)
            S[((size_t)(jh * BB + b) * NN + i0 + i) * HEADS + h2] = redS[h2][i] + redS[h2 + 4][i];
    }
}

// ---------------- Kernel C: combine partials + final projection ----------------
// grid 512 blocks x 256 thr; thread handles one k-pair (2 consecutive k) for all 4 batches.
__global__ __launch_bounds__(256) void k_proj(
    const _Float16* __restrict__ P, const float* __restrict__ S,
    const float* __restrict__ W_out, float* __restrict__ dout)
{
    const int t = threadIdx.x;
    const int k = blockIdx.x * 512 + t * 2;
    const int i = k >> 7;
    const int h = (k >> 5) & 3;

    float wf0[16], wf1[16];
    {
        const float4* wr = (const float4*)(W_out + (size_t)k * NQ);
#pragma unroll
        for (int q4 = 0; q4 < 4; ++q4) {
            const float4 a = wr[q4];
            wf0[q4 * 4 + 0] = a.x; wf0[q4 * 4 + 1] = a.y; wf0[q4 * 4 + 2] = a.z; wf0[q4 * 4 + 3] = a.w;
            const float4 c = wr[4 + q4];
            wf1[q4 * 4 + 0] = c.x; wf1[q4 * 4 + 1] = c.y; wf1[q4 * 4 + 2] = c.z; wf1[q4 * 4 + 3] = c.w;
        }
    }

    float acc[64];
#pragma unroll
    for (int b = 0; b < 4; ++b) {
        const half2 p0 = *(const half2*)(P + (size_t)b * KTOT + k);
        const half2 p1 = *(const half2*)(P + (size_t)(BB + b) * KTOT + k);
        const float rs = S[((size_t)b * NN + i) * HEADS + h] +
                         S[((size_t)(BB + b) * NN + i) * HEADS + h];
        const float inv = __builtin_amdgcn_rcpf(rs);
        const float a0 = ((float)p0[0] + (float)p1[0]) * inv;
        const float a1 = ((float)p0[1] + (float)p1[1]) * inv;
#pragma unroll
        for (int q = 0; q < 16; ++q)
            acc[b * 16 + q] = fmaf(a1, wf1[q], a0 * wf0[q]);
    }

    const int lane = t & 63, wave = t >> 6;
    __shared__ float red[4][64];
#pragma unroll
    for (int r = 0; r < 64; ++r) {
        float v = acc[r];
        v += __shfl_down(v, 32, 64);
        v += __shfl_down(v, 16, 64);
        v += __shfl_down(v, 8, 64);
        v += __shfl_down(v, 4, 64);
        v += __shfl_down(v, 2, 64);
        v += __shfl_down(v, 1, 64);
        if (lane == 0) red[wave][r] = v;
    }
    __syncthreads();
    if (t < 64) {
        const float v = red[0][t] + red[1][t] + red[2][t] + red[3][t];
        atomicAdd(&dout[t], v);
    }
}

extern "C" void kernel_launch(void* const* d_in, const int* in_sizes, int n_in,
                              void* d_out, int out_size, void* d_ws, size_t ws_size,
                              hipStream_t stream)
{
    const float* x       = (const float*)d_in[0];
    const int*   adj     = (const int*)d_in[1];
    const float* W_in    = (const float*)d_in[2];
    const float* b_in    = (const float*)d_in[3];
    const float* att_src = (const float*)d_in[4];
    const float* att_dst = (const float*)d_in[5];
    const float* W_out   = (const float*)d_in[6];
    const float* b_out   = (const float*)d_in[7];
    float* out = (float*)d_out;

    char* ws = (char*)d_ws;
    _Float16* P  = (_Float16*)ws;                                   // 2*BB*N*HID f16 = 4 MB
    float* S     = (float*)(ws + sizeof(_Float16) * 2 * (size_t)BB * KTOT);   // 2*BB*N*4 f32 = 256 KB
    float* srcA  = S + 2 * (size_t)BB * NN * HEADS;                 // 128 KB
    float* dstA  = srcA + (size_t)BB * HEADS * NN;                  // 128 KB
    _Float16* hH = (_Float16*)(dstA + (size_t)BB * HEADS * NN);     // 2 MB
    unsigned* adjbw = (unsigned*)((char*)hH + sizeof(_Float16) * (size_t)BB * KTOT); // 512 KB

    k_hidden<<<BB * NN / 16, 256, 0, stream>>>(x, W_in, b_in, att_src, att_dst, hH, srcA, dstA);
    k_adjb<<<NN * (NN / 64) / 4, 256, 0, stream>>>(adj, adjbw, b_out, out);
    k_attn<<<2 * BB * (NN / 16), 512, 0, stream>>>(adjbw, hH, srcA, dstA, P, S);
    k_proj<<<KTOT / 512, 256, 0, stream>>>(P, S, W_out, out);
}

// Round 6
// 91.497 us; speedup vs baseline: 1.0773x; 1.0773x over previous
//
#include <hip/hip_runtime.h>
#include <math.h>

#define BB 4
#define NN 2048
#define CIN 64
#define HID 128
#define HEADS 4
#define DD 32
#define NQ 16
#define KTOT (NN*HID) // 262144
#define LOG2E 1.44269504088896340736f
#define NEGBIG_BITS 0xC2C80000u   // -100.0f

typedef __attribute__((ext_vector_type(8))) _Float16 half8;
typedef __attribute__((ext_vector_type(4))) _Float16 half4;
typedef __attribute__((ext_vector_type(2))) _Float16 half2;
typedef __attribute__((ext_vector_type(4))) float f32x4;
typedef __attribute__((ext_vector_type(4))) unsigned uint4v;

// ---------------- Kernel A: h = x@W_in + b (f16 out), alpha_src/dst (pre-scaled by log2e) ----
__global__ __launch_bounds__(256) void k_hidden(
    const float* __restrict__ x, const float* __restrict__ W_in,
    const float* __restrict__ b_in, const float* __restrict__ att_src,
    const float* __restrict__ att_dst, _Float16* __restrict__ hH,
    float* __restrict__ srcA, float* __restrict__ dstA)
{
    __shared__ float Wl[CIN * HID];   // 32 KB
    __shared__ float xl[16][CIN];     // 4 KB
    const int t = threadIdx.x;
    const int jj0 = blockIdx.x * 16;

    {
        const float4* Ws = (const float4*)W_in;
        float4* Wd = (float4*)Wl;
#pragma unroll
        for (int u = 0; u < 8; ++u) Wd[t + 256 * u] = Ws[t + 256 * u];
        ((float4*)&xl[0][0])[t] = ((const float4*)(x + (size_t)jj0 * CIN))[t];
    }
    __syncthreads();

    const int c = t & 127, rg = t >> 7;
    const int b = jj0 >> 11, j0 = jj0 & (NN - 1);
    const int h = c >> 5;

    float acc[8];
    const float bc = b_in[c];
#pragma unroll
    for (int rr = 0; rr < 8; ++rr) acc[rr] = bc;

#pragma unroll
    for (int k4 = 0; k4 < CIN; k4 += 4) {
        const float w0 = Wl[(k4 + 0) * HID + c];
        const float w1 = Wl[(k4 + 1) * HID + c];
        const float w2 = Wl[(k4 + 2) * HID + c];
        const float w3 = Wl[(k4 + 3) * HID + c];
#pragma unroll
        for (int rr = 0; rr < 8; ++rr) {
            const float4 xv = *(const float4*)&xl[rg * 8 + rr][k4];
            acc[rr] = fmaf(xv.w, w3, fmaf(xv.z, w2, fmaf(xv.y, w1, fmaf(xv.x, w0, acc[rr]))));
        }
    }

    half8 hv;
#pragma unroll
    for (int rr = 0; rr < 8; ++rr) hv[rr] = (_Float16)acc[rr];
    *(half8*)(hH + (size_t)(b * HID + c) * NN + j0 + rg * 8) = hv;

    const float as = att_src[c], ad = att_dst[c];
#pragma unroll
    for (int rr = 0; rr < 8; ++rr) {
        float vs = acc[rr] * as, vd = acc[rr] * ad;
#pragma unroll
        for (int m = 16; m >= 1; m >>= 1) {
            vs += __shfl_xor(vs, m, 64);
            vd += __shfl_xor(vd, m, 64);
        }
        if ((t & 31) == 0) {
            srcA[(size_t)(b * HEADS + h) * NN + j0 + rg * 8 + rr] = vs * LOG2E;
            dstA[(size_t)(b * HEADS + h) * NN + j0 + rg * 8 + rr] = vd * LOG2E;
        }
    }
}

// ---------------- k_adjb: adj -> bitmask (8 ints/thread); block 0 inits d_out ----------------
__global__ __launch_bounds__(256) void k_adjb(const int* __restrict__ adj,
                                              unsigned* __restrict__ adjb,
                                              const float* __restrict__ b_out,
                                              float* __restrict__ dout)
{
    const int t = threadIdx.x;
    if (blockIdx.x == 0 && t < 64) dout[t] = b_out[t & 15];
    const int gid = blockIdx.x * 256 + t;              // 0 .. N*N/8-1
    const int lane = t & 63;
    const int4* p = (const int4*)(adj + (size_t)gid * 8);
    const int4 a = p[0], b = p[1];
    unsigned byte =
        (a.x != 0 ? 1u : 0u)  | (a.y != 0 ? 2u : 0u)  | (a.z != 0 ? 4u : 0u)  | (a.w != 0 ? 8u : 0u) |
        (b.x != 0 ? 16u : 0u) | (b.y != 0 ? 32u : 0u) | (b.z != 0 ? 64u : 0u) | (b.w != 0 ? 128u : 0u);
    unsigned u = byte | (((unsigned)__shfl_xor((int)byte, 1, 64)) << 8);
    u = u | (((unsigned)__shfl_xor((int)u, 2, 64)) << 16);
    if ((lane & 3) == 0) adjb[gid >> 2] = u;
}

// ---------------- Kernel B: MFMA flash-GAT, j-split partials, sw-pipelined ----------------
// grid 1024 = (jh, b, 16-row i-tile); 8 waves = 4 heads x 2 j-quarters (512 j each)
__global__ __launch_bounds__(512, 4) void k_attn(
    const unsigned* __restrict__ adjb, const _Float16* __restrict__ hH,
    const float* __restrict__ srcA, const float* __restrict__ dstA,
    _Float16* __restrict__ P, float* __restrict__ S)
{
    __shared__ float redA[8][16][36];       // 18.4 KB
    __shared__ float redS[8][16];

    const int t = threadIdx.x;
    const int lane = t & 63;
    const int w = t >> 6;
    const int h = w & 3;
    const int bx = blockIdx.x;
    const int jh = bx >> 9;
    const int b = (bx >> 7) & 3;
    const int i0 = (bx & 127) * 16;
    const int jstart = jh * 1024 + (w >> 2) * 512;

    const int r16 = lane & 15;
    const int g = lane >> 4;
    const float srci = srcA[(size_t)(b * HEADS + h) * NN + i0 + r16];
    const uint2* adjrow2 = (const uint2*)(adjb + (size_t)(i0 + r16) * (NN / 32)) + (jstart >> 6);
    const _Float16* bbase = hH + ((size_t)(b * HID) + h * DD + r16) * NN + jstart + 8 * g;
    const float4* dst4 = (const float4*)(dstA + (size_t)(b * HEADS + h) * NN + jstart) + 2 * g;

    f32x4 acc0 = {0.f, 0.f, 0.f, 0.f};
    f32x4 acc1 = {0.f, 0.f, 0.f, 0.f};
    f32x4 accS = {0.f, 0.f, 0.f, 0.f};
    const half8 ones = {(_Float16)1.f, (_Float16)1.f, (_Float16)1.f, (_Float16)1.f,
                        (_Float16)1.f, (_Float16)1.f, (_Float16)1.f, (_Float16)1.f};

    // one 32-j MFMA group: word bits -> weights -> 3 MFMAs
    auto GROUP = [&](unsigned word, float4 da, float4 db, half8 bb0, half8 bb1) {
        const unsigned bits = word >> (8 * g);
        const float dv[8] = {da.x, da.y, da.z, da.w, db.x, db.y, db.z, db.w};
        float wv[8];
#pragma unroll
        for (int e = 0; e < 8; ++e) {
            float s = srci + dv[e];
            s = fmaxf(s, 0.2f * s);                                   // leaky relu (log2-scaled)
            const unsigned m = (unsigned)(((int)(bits << (31 - e))) >> 31);  // bit e -> 0/-1
            const unsigned su = __builtin_bit_cast(unsigned, s);
            const unsigned sel = (su & m) | (NEGBIG_BITS & ~m);       // v_bfi pattern
            wv[e] = __builtin_amdgcn_exp2f(__builtin_bit_cast(float, sel));
        }
        uint4v uu;
        uu[0] = __builtin_bit_cast(unsigned, __builtin_amdgcn_cvt_pkrtz(wv[0], wv[1]));
        uu[1] = __builtin_bit_cast(unsigned, __builtin_amdgcn_cvt_pkrtz(wv[2], wv[3]));
        uu[2] = __builtin_bit_cast(unsigned, __builtin_amdgcn_cvt_pkrtz(wv[4], wv[5]));
        uu[3] = __builtin_bit_cast(unsigned, __builtin_amdgcn_cvt_pkrtz(wv[6], wv[7]));
        const half8 af = __builtin_bit_cast(half8, uu);
        acc0 = __builtin_amdgcn_mfma_f32_16x16x32_f16(af, bb0, acc0, 0, 0, 0);
        acc1 = __builtin_amdgcn_mfma_f32_16x16x32_f16(af, bb1, acc1, 0, 0, 0);
        accS = __builtin_amdgcn_mfma_f32_16x16x32_f16(af, ones, accS, 0, 0, 0);
    };

    // prime A-buffer with iteration 0
    uint2 awA = adjrow2[0];
    half8 bA0 = *(const half8*)(bbase);
    half8 bA1 = *(const half8*)(bbase + 32);
    half8 bA2 = *(const half8*)(bbase + 16 * NN);
    half8 bA3 = *(const half8*)(bbase + 16 * NN + 32);
    float4 dA0 = dst4[0], dA1 = dst4[1], dA2 = dst4[8], dA3 = dst4[9];

#pragma unroll
    for (int p = 0; p < 4; ++p) {
        const int itB = 2 * p + 1;
        // prefetch B-buffer (iteration itB)
        const uint2 awB = adjrow2[itB];
        const half8 bB0 = *(const half8*)(bbase + itB * 64);
        const half8 bB1 = *(const half8*)(bbase + itB * 64 + 32);
        const half8 bB2 = *(const half8*)(bbase + 16 * NN + itB * 64);
        const half8 bB3 = *(const half8*)(bbase + 16 * NN + itB * 64 + 32);
        const float4 dB0 = dst4[itB * 16], dB1 = dst4[itB * 16 + 1];
        const float4 dB2 = dst4[itB * 16 + 8], dB3 = dst4[itB * 16 + 9];

        // compute A (iteration 2p)
        GROUP(awA.x, dA0, dA1, bA0, bA2);
        GROUP(awA.y, dA2, dA3, bA1, bA3);

        // prefetch A-buffer (iteration 2p+2)
        if (p < 3) {
            const int itA = 2 * p + 2;
            awA = adjrow2[itA];
            bA0 = *(const half8*)(bbase + itA * 64);
            bA1 = *(const half8*)(bbase + itA * 64 + 32);
            bA2 = *(const half8*)(bbase + 16 * NN + itA * 64);
            bA3 = *(const half8*)(bbase + 16 * NN + itA * 64 + 32);
            dA0 = dst4[itA * 16]; dA1 = dst4[itA * 16 + 1];
            dA2 = dst4[itA * 16 + 8]; dA3 = dst4[itA * 16 + 9];
        }

        // compute B (iteration 2p+1)
        GROUP(awB.x, dB0, dB1, bB0, bB2);
        GROUP(awB.y, dB2, dB3, bB1, bB3);
    }

    // write partial tiles (C layout: col(i)=lane&15, row(d)=4*g+reg)
#pragma unroll
    for (int r = 0; r < 4; ++r) {
        redA[w][4 * g + r][r16]      = acc0[r];
        redA[w][4 * g + r][16 + r16] = acc1[r];
    }
    if (r16 == 0) {
#pragma unroll
        for (int r = 0; r < 4; ++r) redS[w][4 * g + r] = accS[r];
    }
    __syncthreads();

    // combine the two j-quarters, pack f16, store partials
    {
        const int i = t >> 5;
        const int q = t & 31;
        const int h2 = q >> 3;
        const int d0 = (q & 7) * 4;
        const float4 v0 = *(const float4*)&redA[h2][i][d0];
        const float4 v1 = *(const float4*)&redA[h2 + 4][i][d0];
        const half2 lo = __builtin_bit_cast(half2, __builtin_amdgcn_cvt_pkrtz(v0.x + v1.x, v0.y + v1.y));
        const half2 hi = __builtin_bit_cast(half2, __builtin_amdgcn_cvt_pkrtz(v0.z + v1.z, v0.w + v1.w));
        half4 o; o[0] = lo[0]; o[1] = lo[1]; o[2] = hi[0]; o[3] = hi[1];
        *(half4*)(P + ((size_t)(jh * BB + b) * NN + i0 + i) * HID + h2 * DD + d0) = o;
        if ((q & 7) == 0)
            S[((size_t)(jh * BB + b) * NN + i0 + i) * HEADS + h2] = redS[h2][i] + redS[h2 + 4][i];
    }
}

// ---------------- Kernel C: combine partials + final projection ----------------
__global__ __launch_bounds__(256) void k_proj(
    const _Float16* __restrict__ P, const float* __restrict__ S,
    const float* __restrict__ W_out, float* __restrict__ dout)
{
    const int t = threadIdx.x;
    const int k = blockIdx.x * 512 + t * 2;
    const int i = k >> 7;
    const int h = (k >> 5) & 3;

    float wf0[16], wf1[16];
    {
        const float4* wr = (const float4*)(W_out + (size_t)k * NQ);
#pragma unroll
        for (int q4 = 0; q4 < 4; ++q4) {
            const float4 a = wr[q4];
            wf0[q4 * 4 + 0] = a.x; wf0[q4 * 4 + 1] = a.y; wf0[q4 * 4 + 2] = a.z; wf0[q4 * 4 + 3] = a.w;
            const float4 c = wr[4 + q4];
            wf1[q4 * 4 + 0] = c.x; wf1[q4 * 4 + 1] = c.y; wf1[q4 * 4 + 2] = c.z; wf1[q4 * 4 + 3] = c.w;
        }
    }

    float acc[64];
#pragma unroll
    for (int b = 0; b < 4; ++b) {
        const half2 p0 = *(const half2*)(P + (size_t)b * KTOT + k);
        const half2 p1 = *(const half2*)(P + (size_t)(BB + b) * KTOT + k);
        const float rs = S[((size_t)b * NN + i) * HEADS + h] +
                         S[((size_t)(BB + b) * NN + i) * HEADS + h];
        const float inv = __builtin_amdgcn_rcpf(rs);
        const float a0 = ((float)p0[0] + (float)p1[0]) * inv;
        const float a1 = ((float)p0[1] + (float)p1[1]) * inv;
#pragma unroll
        for (int q = 0; q < 16; ++q)
            acc[b * 16 + q] = fmaf(a1, wf1[q], a0 * wf0[q]);
    }

    const int lane = t & 63, wave = t >> 6;
    __shared__ float red[4][64];
#pragma unroll
    for (int r = 0; r < 64; ++r) {
        float v = acc[r];
        v += __shfl_down(v, 32, 64);
        v += __shfl_down(v, 16, 64);
        v += __shfl_down(v, 8, 64);
        v += __shfl_down(v, 4, 64);
        v += __shfl_down(v, 2, 64);
        v += __shfl_down(v, 1, 64);
        if (lane == 0) red[wave][r] = v;
    }
    __syncthreads();
    if (t < 64) {
        const float v = red[0][t] + red[1][t] + red[2][t] + red[3][t];
        atomicAdd(&dout[t], v);
    }
}

extern "C" void kernel_launch(void* const* d_in, const int* in_sizes, int n_in,
                              void* d_out, int out_size, void* d_ws, size_t ws_size,
                              hipStream_t stream)
{
    const float* x       = (const float*)d_in[0];
    const int*   adj     = (const int*)d_in[1];
    const float* W_in    = (const float*)d_in[2];
    const float* b_in    = (const float*)d_in[3];
    const float* att_src = (const float*)d_in[4];
    const float* att_dst = (const float*)d_in[5];
    const float* W_out   = (const float*)d_in[6];
    const float* b_out   = (const float*)d_in[7];
    float* out = (float*)d_out;

    char* ws = (char*)d_ws;
    _Float16* P  = (_Float16*)ws;                                   // 4 MB
    float* S     = (float*)(ws + sizeof(_Float16) * 2 * (size_t)BB * KTOT);   // 256 KB
    float* srcA  = S + 2 * (size_t)BB * NN * HEADS;                 // 128 KB
    float* dstA  = srcA + (size_t)BB * HEADS * NN;                  // 128 KB
    _Float16* hH = (_Float16*)(dstA + (size_t)BB * HEADS * NN);     // 2 MB
    unsigned* adjbw = (unsigned*)((char*)hH + sizeof(_Float16) * (size_t)BB * KTOT); // 512 KB

    k_hidden<<<BB * NN / 16, 256, 0, stream>>>(x, W_in, b_in, att_src, att_dst, hH, srcA, dstA);
    k_adjb<<<NN * NN / 8 / 256, 256, 0, stream>>>(adj, adjbw, b_out, out);
    k_attn<<<2 * BB * (NN / 16), 512, 0, stream>>>(adjbw, hH, srcA, dstA, P, S);
    k_proj<<<KTOT / 512, 256, 0, stream>>>(P, S, W_out, out);
}

// Round 7
// 89.181 us; speedup vs baseline: 1.1053x; 1.0260x over previous
//
#include <hip/hip_runtime.h>
#include <math.h>

#define BB 4
#define NN 2048
#define CIN 64
#define HID 128
#define HEADS 4
#define DD 32
#define NQ 16
#define KTOT (NN*HID) // 262144
#define LOG2E 1.44269504088896340736f
#define NEGBIG_BITS 0xC2C80000u   // -100.0f

typedef __attribute__((ext_vector_type(8))) _Float16 half8;
typedef __attribute__((ext_vector_type(4))) _Float16 half4;
typedef __attribute__((ext_vector_type(2))) _Float16 half2;
typedef __attribute__((ext_vector_type(4))) float f32x4;
typedef __attribute__((ext_vector_type(4))) unsigned uint4v;

// ---------------- Kernel A: h = x@W_in + b (f16 out), alpha_src/dst (pre-scaled by log2e) ----
// 1024 blocks x 256 thr; block = 8 rows; thread = (c, 4 rows).
__global__ __launch_bounds__(256) void k_hidden(
    const float* __restrict__ x, const float* __restrict__ W_in,
    const float* __restrict__ b_in, const float* __restrict__ att_src,
    const float* __restrict__ att_dst, _Float16* __restrict__ hH,
    float* __restrict__ srcA, float* __restrict__ dstA)
{
    __shared__ float Wl[CIN * HID];   // 32 KB
    __shared__ float xl[8][CIN];      // 2 KB
    const int t = threadIdx.x;
    const int jj0 = blockIdx.x * 8;

    {
        const float4* Ws = (const float4*)W_in;
        float4* Wd = (float4*)Wl;
#pragma unroll
        for (int u = 0; u < 8; ++u) Wd[t + 256 * u] = Ws[t + 256 * u];
        if (t < 128) ((float4*)&xl[0][0])[t] = ((const float4*)(x + (size_t)jj0 * CIN))[t];
    }
    __syncthreads();

    const int c = t & 127, rg = t >> 7;
    const int b = jj0 >> 11, j0 = (jj0 & (NN - 1)) + rg * 4;
    const int h = c >> 5;

    float acc[4];
    const float bc = b_in[c];
#pragma unroll
    for (int rr = 0; rr < 4; ++rr) acc[rr] = bc;

#pragma unroll
    for (int k4 = 0; k4 < CIN; k4 += 4) {
        const float w0 = Wl[(k4 + 0) * HID + c];
        const float w1 = Wl[(k4 + 1) * HID + c];
        const float w2 = Wl[(k4 + 2) * HID + c];
        const float w3 = Wl[(k4 + 3) * HID + c];
#pragma unroll
        for (int rr = 0; rr < 4; ++rr) {
            const float4 xv = *(const float4*)&xl[rg * 4 + rr][k4];
            acc[rr] = fmaf(xv.w, w3, fmaf(xv.z, w2, fmaf(xv.y, w1, fmaf(xv.x, w0, acc[rr]))));
        }
    }

    half4 hv;
#pragma unroll
    for (int rr = 0; rr < 4; ++rr) hv[rr] = (_Float16)acc[rr];
    *(half4*)(hH + (size_t)(b * HID + c) * NN + j0) = hv;

    const float as = att_src[c], ad = att_dst[c];
#pragma unroll
    for (int rr = 0; rr < 4; ++rr) {
        float vs = acc[rr] * as, vd = acc[rr] * ad;
#pragma unroll
        for (int m = 16; m >= 1; m >>= 1) {
            vs += __shfl_xor(vs, m, 64);
            vd += __shfl_xor(vd, m, 64);
        }
        if ((t & 31) == 0) {
            srcA[(size_t)(b * HEADS + h) * NN + j0 + rr] = vs * LOG2E;
            dstA[(size_t)(b * HEADS + h) * NN + j0 + rr] = vd * LOG2E;
        }
    }
}

// ---------------- k_adjb: adj -> bitmask (8 ints/thread); block 0 inits d_out ----------------
__global__ __launch_bounds__(256) void k_adjb(const int* __restrict__ adj,
                                              unsigned* __restrict__ adjb,
                                              const float* __restrict__ b_out,
                                              float* __restrict__ dout)
{
    const int t = threadIdx.x;
    if (blockIdx.x == 0 && t < 64) dout[t] = b_out[t & 15];
    const int gid = blockIdx.x * 256 + t;              // 0 .. N*N/8-1
    const int lane = t & 63;
    const int4* p = (const int4*)(adj + (size_t)gid * 8);
    const int4 a = p[0], b = p[1];
    unsigned byte =
        (a.x != 0 ? 1u : 0u)  | (a.y != 0 ? 2u : 0u)  | (a.z != 0 ? 4u : 0u)  | (a.w != 0 ? 8u : 0u) |
        (b.x != 0 ? 16u : 0u) | (b.y != 0 ? 32u : 0u) | (b.z != 0 ? 64u : 0u) | (b.w != 0 ? 128u : 0u);
    unsigned u = byte | (((unsigned)__shfl_xor((int)byte, 1, 64)) << 8);
    u = u | (((unsigned)__shfl_xor((int)u, 2, 64)) << 16);
    if ((lane & 3) == 0) adjb[gid >> 2] = u;
}

// ---------------- Kernel B: MFMA flash-GAT, j-split partials, fenced sw-pipeline ----------------
// grid 1024 = (jh, b, 16-row i-tile); 8 waves = 4 heads x 2 j-quarters (512 j each)
__global__ __launch_bounds__(512, 4) void k_attn(
    const unsigned* __restrict__ adjb, const _Float16* __restrict__ hH,
    const float* __restrict__ srcA, const float* __restrict__ dstA,
    _Float16* __restrict__ P, float* __restrict__ S)
{
    __shared__ float redA[8][16][36];       // 18.4 KB
    __shared__ float redS[8][16];

    const int t = threadIdx.x;
    const int lane = t & 63;
    const int w = t >> 6;
    const int h = w & 3;
    const int bx = blockIdx.x;
    const int jh = bx >> 9;
    const int b = (bx >> 7) & 3;
    const int i0 = (bx & 127) * 16;
    const int jstart = jh * 1024 + (w >> 2) * 512;

    const int r16 = lane & 15;
    const int g = lane >> 4;
    const float srci = srcA[(size_t)(b * HEADS + h) * NN + i0 + r16];
    const uint2* adjrow2 = (const uint2*)(adjb + (size_t)(i0 + r16) * (NN / 32)) + (jstart >> 6);
    const _Float16* bbase = hH + ((size_t)(b * HID) + h * DD + r16) * NN + jstart + 8 * g;
    const float4* dst4 = (const float4*)(dstA + (size_t)(b * HEADS + h) * NN + jstart) + 2 * g;

    f32x4 acc0 = {0.f, 0.f, 0.f, 0.f};
    f32x4 acc1 = {0.f, 0.f, 0.f, 0.f};
    f32x4 accS = {0.f, 0.f, 0.f, 0.f};
    const half8 ones = {(_Float16)1.f, (_Float16)1.f, (_Float16)1.f, (_Float16)1.f,
                        (_Float16)1.f, (_Float16)1.f, (_Float16)1.f, (_Float16)1.f};

    // one 32-j MFMA group: word bits -> weights -> 3 MFMAs
    auto GROUP = [&](unsigned word, float4 da, float4 db, half8 bb0, half8 bb1) {
        const unsigned bits = word >> (8 * g);
        const float dv[8] = {da.x, da.y, da.z, da.w, db.x, db.y, db.z, db.w};
        float wv[8];
#pragma unroll
        for (int e = 0; e < 8; ++e) {
            float s = srci + dv[e];
            s = fmaxf(s, 0.2f * s);                                   // leaky relu (log2-scaled)
            const unsigned m = (unsigned)(((int)(bits << (31 - e))) >> 31);  // bit e -> 0/-1
            const unsigned su = __builtin_bit_cast(unsigned, s);
            const unsigned sel = (su & m) | (NEGBIG_BITS & ~m);       // v_bfi pattern
            wv[e] = __builtin_amdgcn_exp2f(__builtin_bit_cast(float, sel));
        }
        uint4v uu;
        uu[0] = __builtin_bit_cast(unsigned, __builtin_amdgcn_cvt_pkrtz(wv[0], wv[1]));
        uu[1] = __builtin_bit_cast(unsigned, __builtin_amdgcn_cvt_pkrtz(wv[2], wv[3]));
        uu[2] = __builtin_bit_cast(unsigned, __builtin_amdgcn_cvt_pkrtz(wv[4], wv[5]));
        uu[3] = __builtin_bit_cast(unsigned, __builtin_amdgcn_cvt_pkrtz(wv[6], wv[7]));
        const half8 af = __builtin_bit_cast(half8, uu);
        acc0 = __builtin_amdgcn_mfma_f32_16x16x32_f16(af, bb0, acc0, 0, 0, 0);
        acc1 = __builtin_amdgcn_mfma_f32_16x16x32_f16(af, bb1, acc1, 0, 0, 0);
        accS = __builtin_amdgcn_mfma_f32_16x16x32_f16(af, ones, accS, 0, 0, 0);
    };

    // prime A-buffer with iteration 0
    uint2 awA = adjrow2[0];
    half8 bA0 = *(const half8*)(bbase);
    half8 bA1 = *(const half8*)(bbase + 32);
    half8 bA2 = *(const half8*)(bbase + 16 * NN);
    half8 bA3 = *(const half8*)(bbase + 16 * NN + 32);
    float4 dA0 = dst4[0], dA1 = dst4[1], dA2 = dst4[8], dA3 = dst4[9];
    __builtin_amdgcn_sched_barrier(0);

#pragma unroll
    for (int p = 0; p < 4; ++p) {
        const int itB = 2 * p + 1;
        // issue B-buffer loads (iteration itB); fence keeps them here (not sunk)
        const uint2 awB = adjrow2[itB];
        const half8 bB0 = *(const half8*)(bbase + itB * 64);
        const half8 bB1 = *(const half8*)(bbase + itB * 64 + 32);
        const half8 bB2 = *(const half8*)(bbase + 16 * NN + itB * 64);
        const half8 bB3 = *(const half8*)(bbase + 16 * NN + itB * 64 + 32);
        const float4 dB0 = dst4[itB * 16], dB1 = dst4[itB * 16 + 1];
        const float4 dB2 = dst4[itB * 16 + 8], dB3 = dst4[itB * 16 + 9];
        __builtin_amdgcn_sched_barrier(0);

        // compute A (iteration 2p) while B-loads are in flight
        GROUP(awA.x, dA0, dA1, bA0, bA2);
        GROUP(awA.y, dA2, dA3, bA1, bA3);
        __builtin_amdgcn_sched_barrier(0);

        // issue A-buffer loads (iteration 2p+2)
        if (p < 3) {
            const int itA = 2 * p + 2;
            awA = adjrow2[itA];
            bA0 = *(const half8*)(bbase + itA * 64);
            bA1 = *(const half8*)(bbase + itA * 64 + 32);
            bA2 = *(const half8*)(bbase + 16 * NN + itA * 64);
            bA3 = *(const half8*)(bbase + 16 * NN + itA * 64 + 32);
            dA0 = dst4[itA * 16]; dA1 = dst4[itA * 16 + 1];
            dA2 = dst4[itA * 16 + 8]; dA3 = dst4[itA * 16 + 9];
        }
        __builtin_amdgcn_sched_barrier(0);

        // compute B (iteration 2p+1) while A-loads are in flight
        GROUP(awB.x, dB0, dB1, bB0, bB2);
        GROUP(awB.y, dB2, dB3, bB1, bB3);
        __builtin_amdgcn_sched_barrier(0);
    }

    // write partial tiles (C layout: col(i)=lane&15, row(d)=4*g+reg)
#pragma unroll
    for (int r = 0; r < 4; ++r) {
        redA[w][4 * g + r][r16]      = acc0[r];
        redA[w][4 * g + r][16 + r16] = acc1[r];
    }
    if (r16 == 0) {
#pragma unroll
        for (int r = 0; r < 4; ++r) redS[w][4 * g + r] = accS[r];
    }
    __syncthreads();

    // combine the two j-quarters, pack f16, store partials
    {
        const int i = t >> 5;
        const int q = t & 31;
        const int h2 = q >> 3;
        const int d0 = (q & 7) * 4;
        const float4 v0 = *(const float4*)&redA[h2][i][d0];
        const float4 v1 = *(const float4*)&redA[h2 + 4][i][d0];
        const half2 lo = __builtin_bit_cast(half2, __builtin_amdgcn_cvt_pkrtz(v0.x + v1.x, v0.y + v1.y));
        const half2 hi = __builtin_bit_cast(half2, __builtin_amdgcn_cvt_pkrtz(v0.z + v1.z, v0.w + v1.w));
        half4 o; o[0] = lo[0]; o[1] = lo[1]; o[2] = hi[0]; o[3] = hi[1];
        *(half4*)(P + ((size_t)(jh * BB + b) * NN + i0 + i) * HID + h2 * DD + d0) = o;
        if ((q & 7) == 0)
            S[((size_t)(jh * BB + b) * NN + i0 + i) * HEADS + h2] = redS[h2][i] + redS[h2 + 4][i];
    }
}

// ---------------- Kernel C: combine partials + final projection ----------------
// 1024 blocks x 256 thr; thread = (q, b, k-slice of 64 consecutive k) -> one scalar acc.
__global__ __launch_bounds__(256) void k_proj(
    const _Float16* __restrict__ P, const float* __restrict__ S,
    const float* __restrict__ W_out, float* __restrict__ dout)
{
    const int t = threadIdx.x;
    const int q = t & 15;
    const int b = (t >> 4) & 3;
    const int sl = t >> 6;
    const int k0 = blockIdx.x * 256 + sl * 64;
    const int i = k0 >> 7;                         // constant over the 64-k slice

    const _Float16* p0 = P + (size_t)b * KTOT + k0;
    const _Float16* p1 = P + (size_t)(BB + b) * KTOT + k0;
    const float* wp = W_out + (size_t)k0 * NQ + q;

    float acc = 0.f;
#pragma unroll
    for (int seg = 0; seg < 2; ++seg) {
        const int h = ((k0 + seg * 32) >> 5) & 3;
        const float rs = S[((size_t)b * NN + i) * HEADS + h] +
                         S[((size_t)(BB + b) * NN + i) * HEADS + h];
        const float inv = __builtin_amdgcn_rcpf(rs);
#pragma unroll
        for (int k8 = 0; k8 < 4; ++k8) {
            const int kk = seg * 32 + k8 * 8;
            const half8 a0 = *(const half8*)(p0 + kk);
            const half8 a1 = *(const half8*)(p1 + kk);
#pragma unroll
            for (int e = 0; e < 8; ++e) {
                const float a = ((float)a0[e] + (float)a1[e]) * inv;
                acc = fmaf(a, wp[(kk + e) * NQ], acc);
            }
        }
    }

    __shared__ float red[256];
    red[t] = acc;
    __syncthreads();
    if (t < 64)
        atomicAdd(&dout[t], red[t] + red[t + 64] + red[t + 128] + red[t + 192]);
}

extern "C" void kernel_launch(void* const* d_in, const int* in_sizes, int n_in,
                              void* d_out, int out_size, void* d_ws, size_t ws_size,
                              hipStream_t stream)
{
    const float* x       = (const float*)d_in[0];
    const int*   adj     = (const int*)d_in[1];
    const float* W_in    = (const float*)d_in[2];
    const float* b_in    = (const float*)d_in[3];
    const float* att_src = (const float*)d_in[4];
    const float* att_dst = (const float*)d_in[5];
    const float* W_out   = (const float*)d_in[6];
    const float* b_out   = (const float*)d_in[7];
    float* out = (float*)d_out;

    char* ws = (char*)d_ws;
    _Float16* P  = (_Float16*)ws;                                   // 4 MB
    float* S     = (float*)(ws + sizeof(_Float16) * 2 * (size_t)BB * KTOT);   // 256 KB
    float* srcA  = S + 2 * (size_t)BB * NN * HEADS;                 // 128 KB
    float* dstA  = srcA + (size_t)BB * HEADS * NN;                  // 128 KB
    _Float16* hH = (_Float16*)(dstA + (size_t)BB * HEADS * NN);     // 2 MB
    unsigned* adjbw = (unsigned*)((char*)hH + sizeof(_Float16) * (size_t)BB * KTOT); // 512 KB

    k_hidden<<<BB * NN / 8, 256, 0, stream>>>(x, W_in, b_in, att_src, att_dst, hH, srcA, dstA);
    k_adjb<<<NN * NN / 8 / 256, 256, 0, stream>>>(adj, adjbw, b_out, out);
    k_attn<<<2 * BB * (NN / 16), 512, 0, stream>>>(adjbw, hH, srcA, dstA, P, S);
    k_proj<<<KTOT / 256, 256, 0, stream>>>(P, S, W_out, out);
}

// Round 9
// 74.793 us; speedup vs baseline: 1.3179x; 1.1924x over previous
//
#include <hip/hip_runtime.h>
#include <math.h>

#define BB 4
#define NN 2048
#define CIN 64
#define HID 128
#define HEADS 4
#define DD 32
#define NQ 16
#define KTOT (NN*HID) // 262144
#define LOG2E 1.44269504088896340736f
#define NEGBIG_BITS 0xC2C80000u   // -100.0f

#define HB 512        // k_pre blocks doing hidden (16 rows each)
#define AB 2048       // k_pre blocks doing adj bitmask

typedef __attribute__((ext_vector_type(8))) _Float16 half8;
typedef __attribute__((ext_vector_type(4))) _Float16 half4;
typedef __attribute__((ext_vector_type(2))) _Float16 half2;
typedef __attribute__((ext_vector_type(4))) float f32x4;
typedef __attribute__((ext_vector_type(4))) unsigned uint4v;

// ---------------- k_pre: hidden GEMM (blocks 0..511) + adj bitmask (blocks 512..2559) ----
__global__ __launch_bounds__(256) void k_pre(
    const float* __restrict__ x, const float* __restrict__ W_in,
    const float* __restrict__ b_in, const float* __restrict__ att_src,
    const float* __restrict__ att_dst, const int* __restrict__ adj,
    _Float16* __restrict__ hH, float* __restrict__ srcA, float* __restrict__ dstA,
    unsigned* __restrict__ adjb, const float* __restrict__ b_out,
    float* __restrict__ dout)
{
    __shared__ float Wl[CIN * HID];   // 32 KB
    __shared__ float xl[16][CIN];     // 4 KB
    const int t = threadIdx.x;

    if (blockIdx.x >= HB) {
        // ---- adj -> bitmask; first adj-block inits d_out ----
        const int bid = blockIdx.x - HB;
        if (bid == 0 && t < 64) dout[t] = b_out[t & 15];
        const int gid = bid * 256 + t;              // 0 .. N*N/8-1
        const int lane = t & 63;
        const int4* p = (const int4*)(adj + (size_t)gid * 8);
        const int4 a = p[0], b = p[1];
        unsigned byte =
            (a.x != 0 ? 1u : 0u)  | (a.y != 0 ? 2u : 0u)  | (a.z != 0 ? 4u : 0u)  | (a.w != 0 ? 8u : 0u) |
            (b.x != 0 ? 16u : 0u) | (b.y != 0 ? 32u : 0u) | (b.z != 0 ? 64u : 0u) | (b.w != 0 ? 128u : 0u);
        unsigned u = byte | (((unsigned)__shfl_xor((int)byte, 1, 64)) << 8);
        u = u | (((unsigned)__shfl_xor((int)u, 2, 64)) << 16);
        if ((lane & 3) == 0) adjb[gid >> 2] = u;
        return;
    }

    // ---- hidden: 16 rows per block ----
    const int jj0 = blockIdx.x * 16;
    {
        const float4* Ws = (const float4*)W_in;
        float4* Wd = (float4*)Wl;
#pragma unroll
        for (int u = 0; u < 8; ++u) Wd[t + 256 * u] = Ws[t + 256 * u];
        ((float4*)&xl[0][0])[t] = ((const float4*)(x + (size_t)jj0 * CIN))[t];
    }
    __syncthreads();

    const int c = t & 127, rg = t >> 7;
    const int b = jj0 >> 11, j0 = (jj0 & (NN - 1)) + rg * 8;
    const int h = c >> 5;

    float acc[8];
    const float bc = b_in[c];
#pragma unroll
    for (int rr = 0; rr < 8; ++rr) acc[rr] = bc;

#pragma unroll
    for (int k4 = 0; k4 < CIN; k4 += 4) {
        const float w0 = Wl[(k4 + 0) * HID + c];
        const float w1 = Wl[(k4 + 1) * HID + c];
        const float w2 = Wl[(k4 + 2) * HID + c];
        const float w3 = Wl[(k4 + 3) * HID + c];
#pragma unroll
        for (int rr = 0; rr < 8; ++rr) {
            const float4 xv = *(const float4*)&xl[rg * 8 + rr][k4];
            acc[rr] = fmaf(xv.w, w3, fmaf(xv.z, w2, fmaf(xv.y, w1, fmaf(xv.x, w0, acc[rr]))));
        }
    }

    half8 hv;
#pragma unroll
    for (int rr = 0; rr < 8; ++rr) hv[rr] = (_Float16)acc[rr];
    *(half8*)(hH + (size_t)(b * HID + c) * NN + j0) = hv;

    const float as = att_src[c], ad = att_dst[c];
#pragma unroll
    for (int rr = 0; rr < 8; ++rr) {
        float vs = acc[rr] * as, vd = acc[rr] * ad;
#pragma unroll
        for (int m = 16; m >= 1; m >>= 1) {
            vs += __shfl_xor(vs, m, 64);
            vd += __shfl_xor(vd, m, 64);
        }
        if ((t & 31) == 0) {
            srcA[(size_t)(b * HEADS + h) * NN + j0 + rr] = vs * LOG2E;
            dstA[(size_t)(b * HEADS + h) * NN + j0 + rr] = vd * LOG2E;
        }
    }
}

// ---------------- Kernel B: MFMA flash-GAT, i-tile=32, j-split partials ----------------
// grid 512 = (jh, b, 32-row i-tile); 8 waves = 4 heads x 2 j-quarters (512 j each)
__global__ __launch_bounds__(512, 4) void k_attn(
    const unsigned* __restrict__ adjb, const _Float16* __restrict__ hH,
    const float* __restrict__ srcA, const float* __restrict__ dstA,
    _Float16* __restrict__ P, float* __restrict__ S)
{
    __shared__ float redA[8][32][36];       // 36.9 KB  [wave][i][d+pad]
    __shared__ float redS[8][32];

    const int t = threadIdx.x;
    const int lane = t & 63;
    const int w = t >> 6;
    const int h = w & 3;
    const int bx = blockIdx.x;
    const int jh = bx >> 8;
    const int b = (bx >> 6) & 3;
    const int i0 = (bx & 63) * 32;
    const int jstart = jh * 1024 + (w >> 2) * 512;

    const int r16 = lane & 15;
    const int g = lane >> 4;
    const float srci0 = srcA[(size_t)(b * HEADS + h) * NN + i0 + r16];
    const float srci1 = srcA[(size_t)(b * HEADS + h) * NN + i0 + 16 + r16];
    const uint2* adjr0 = (const uint2*)(adjb + (size_t)(i0 + r16) * (NN / 32)) + (jstart >> 6);
    const uint2* adjr1 = (const uint2*)(adjb + (size_t)(i0 + 16 + r16) * (NN / 32)) + (jstart >> 6);
    const _Float16* bbase = hH + ((size_t)(b * HID) + h * DD + r16) * NN + jstart + 8 * g;
    const float4* dst4 = (const float4*)(dstA + (size_t)(b * HEADS + h) * NN + jstart) + 2 * g;

    f32x4 acc00 = {0.f, 0.f, 0.f, 0.f};   // i-frag0, d-lo
    f32x4 acc01 = {0.f, 0.f, 0.f, 0.f};   // i-frag0, d-hi
    f32x4 acc10 = {0.f, 0.f, 0.f, 0.f};   // i-frag1, d-lo
    f32x4 acc11 = {0.f, 0.f, 0.f, 0.f};   // i-frag1, d-hi
    f32x4 accS0 = {0.f, 0.f, 0.f, 0.f};
    f32x4 accS1 = {0.f, 0.f, 0.f, 0.f};
    const half8 ones = {(_Float16)1.f, (_Float16)1.f, (_Float16)1.f, (_Float16)1.f,
                        (_Float16)1.f, (_Float16)1.f, (_Float16)1.f, (_Float16)1.f};

    // one 32-j group for one i-frag: bits -> weights (f16 A-frag)
    auto MAKEAF = [&](float srci, unsigned bits, const float* dv) -> half8 {
        float wv[8];
#pragma unroll
        for (int e = 0; e < 8; ++e) {
            float s = srci + dv[e];
            s = fmaxf(s, 0.2f * s);                                   // leaky relu (log2-scaled)
            const unsigned m = (unsigned)(((int)(bits << (31 - e))) >> 31);  // bit e -> 0/-1
            const unsigned su = __builtin_bit_cast(unsigned, s);
            const unsigned sel = (su & m) | (NEGBIG_BITS & ~m);       // v_bfi pattern
            wv[e] = __builtin_amdgcn_exp2f(__builtin_bit_cast(float, sel));
        }
        uint4v uu;
        uu[0] = __builtin_bit_cast(unsigned, __builtin_amdgcn_cvt_pkrtz(wv[0], wv[1]));
        uu[1] = __builtin_bit_cast(unsigned, __builtin_amdgcn_cvt_pkrtz(wv[2], wv[3]));
        uu[2] = __builtin_bit_cast(unsigned, __builtin_amdgcn_cvt_pkrtz(wv[4], wv[5]));
        uu[3] = __builtin_bit_cast(unsigned, __builtin_amdgcn_cvt_pkrtz(wv[6], wv[7]));
        return __builtin_bit_cast(half8, uu);
    };

    // 32-j group: both i-frags + 6 MFMAs
    auto GROUP = [&](unsigned w0, unsigned w1, float4 da, float4 db, half8 bb0, half8 bb1) {
        const unsigned bits0 = w0 >> (8 * g);
        const unsigned bits1 = w1 >> (8 * g);
        const float dv[8] = {da.x, da.y, da.z, da.w, db.x, db.y, db.z, db.w};
        const half8 af0 = MAKEAF(srci0, bits0, dv);
        const half8 af1 = MAKEAF(srci1, bits1, dv);
        acc00 = __builtin_amdgcn_mfma_f32_16x16x32_f16(af0, bb0, acc00, 0, 0, 0);
        acc01 = __builtin_amdgcn_mfma_f32_16x16x32_f16(af0, bb1, acc01, 0, 0, 0);
        acc10 = __builtin_amdgcn_mfma_f32_16x16x32_f16(af1, bb0, acc10, 0, 0, 0);
        acc11 = __builtin_amdgcn_mfma_f32_16x16x32_f16(af1, bb1, acc11, 0, 0, 0);
        accS0 = __builtin_amdgcn_mfma_f32_16x16x32_f16(af0, ones, accS0, 0, 0, 0);
        accS1 = __builtin_amdgcn_mfma_f32_16x16x32_f16(af1, ones, accS1, 0, 0, 0);
    };

    // prime A-buffer (iteration 0): hH + adj only (dst is 16-lane-broadcast, read at use)
    uint2 aA0 = adjr0[0], aA1 = adjr1[0];
    half8 bA0 = *(const half8*)(bbase);
    half8 bA1 = *(const half8*)(bbase + 32);
    half8 bA2 = *(const half8*)(bbase + 16 * NN);
    half8 bA3 = *(const half8*)(bbase + 16 * NN + 32);
    __builtin_amdgcn_sched_barrier(0);

#pragma unroll
    for (int p = 0; p < 4; ++p) {
        const int itB = 2 * p + 1;
        // issue B-buffer loads (iteration itB)
        const uint2 aB0 = adjr0[itB], aB1 = adjr1[itB];
        const half8 bB0 = *(const half8*)(bbase + itB * 64);
        const half8 bB1 = *(const half8*)(bbase + itB * 64 + 32);
        const half8 bB2 = *(const half8*)(bbase + 16 * NN + itB * 64);
        const half8 bB3 = *(const half8*)(bbase + 16 * NN + itB * 64 + 32);
        __builtin_amdgcn_sched_barrier(0);

        {   // compute iteration 2p
            const int it = 2 * p;
            GROUP(aA0.x, aA1.x, dst4[it * 16],     dst4[it * 16 + 1], bA0, bA2);
            GROUP(aA0.y, aA1.y, dst4[it * 16 + 8], dst4[it * 16 + 9], bA1, bA3);
        }
        __builtin_amdgcn_sched_barrier(0);

        // issue A-buffer loads (iteration 2p+2)
        if (p < 3) {
            const int itA = 2 * p + 2;
            aA0 = adjr0[itA]; aA1 = adjr1[itA];
            bA0 = *(const half8*)(bbase + itA * 64);
            bA1 = *(const half8*)(bbase + itA * 64 + 32);
            bA2 = *(const half8*)(bbase + 16 * NN + itA * 64);
            bA3 = *(const half8*)(bbase + 16 * NN + itA * 64 + 32);
        }
        __builtin_amdgcn_sched_barrier(0);

        // compute iteration 2p+1
        GROUP(aB0.x, aB1.x, dst4[itB * 16],     dst4[itB * 16 + 1], bB0, bB2);
        GROUP(aB0.y, aB1.y, dst4[itB * 16 + 8], dst4[itB * 16 + 9], bB1, bB3);
        __builtin_amdgcn_sched_barrier(0);
    }

    // write partial tiles: out[i = 16*if + 4g+r][d = 16*dh + r16]
#pragma unroll
    for (int r = 0; r < 4; ++r) {
        redA[w][ 0 + 4 * g + r][ 0 + r16] = acc00[r];
        redA[w][ 0 + 4 * g + r][16 + r16] = acc01[r];
        redA[w][16 + 4 * g + r][ 0 + r16] = acc10[r];
        redA[w][16 + 4 * g + r][16 + r16] = acc11[r];
    }
    if (r16 == 0) {
#pragma unroll
        for (int r = 0; r < 4; ++r) {
            redS[w][ 0 + 4 * g + r] = accS0[r];
            redS[w][16 + 4 * g + r] = accS1[r];
        }
    }
    __syncthreads();

    // combine the two j-quarters, pack f16, store UNNORMALIZED partials
    // (k_proj does the single normalization by the full rowsum)
    {
        const int i = t & 31;
        const int u = t >> 5;            // 0..15
        const int h2 = u & 3;
        const int d0 = (u >> 2) * 8;
        const float4 va0 = *(const float4*)&redA[h2][i][d0];
        const float4 va1 = *(const float4*)&redA[h2][i][d0 + 4];
        const float4 vb0 = *(const float4*)&redA[h2 + 4][i][d0];
        const float4 vb1 = *(const float4*)&redA[h2 + 4][i][d0 + 4];
        const float rs = redS[h2][i] + redS[h2 + 4][i];
        const half2 q0 = __builtin_bit_cast(half2, __builtin_amdgcn_cvt_pkrtz(va0.x + vb0.x, va0.y + vb0.y));
        const half2 q1 = __builtin_bit_cast(half2, __builtin_amdgcn_cvt_pkrtz(va0.z + vb0.z, va0.w + vb0.w));
        const half2 q2 = __builtin_bit_cast(half2, __builtin_amdgcn_cvt_pkrtz(va1.x + vb1.x, va1.y + vb1.y));
        const half2 q3 = __builtin_bit_cast(half2, __builtin_amdgcn_cvt_pkrtz(va1.z + vb1.z, va1.w + vb1.w));
        half8 o;
        o[0] = q0[0]; o[1] = q0[1]; o[2] = q1[0]; o[3] = q1[1];
        o[4] = q2[0]; o[5] = q2[1]; o[6] = q3[0]; o[7] = q3[1];
        *(half8*)(P + ((size_t)(jh * BB + b) * NN + i0 + i) * HID + h2 * DD + d0) = o;
        if (u < 4)
            S[((size_t)(jh * BB + b) * NN + i0 + i) * HEADS + h2] = rs;
    }
}

// ---------------- Kernel C: combine partials + final projection (W^T staged in LDS) -----
// 1024 blocks x 256 thr; thread = (q, b, 64-k slice) -> one scalar output contribution.
__global__ __launch_bounds__(256) void k_proj(
    const _Float16* __restrict__ P, const float* __restrict__ S,
    const float* __restrict__ W_out, float* __restrict__ dout)
{
    __shared__ float wlT[NQ][260];     // 16.6 KB, W^T for this block's 256 k
    __shared__ float red[256];

    const int t = threadIdx.x;
    const int k0 = blockIdx.x * 256;

    // stage W^T: 4096 floats, coalesced float4 reads, scattered scalar LDS writes
#pragma unroll
    for (int u = 0; u < 4; ++u) {
        const int flat = (u * 256 + t) * 4;            // float index into W_out[k0*16 ..]
        const float4 wv = *(const float4*)(W_out + (size_t)k0 * NQ + flat);
        const int krel = flat >> 4;
        const int q0 = flat & 15;
        wlT[q0 + 0][krel] = wv.x;
        wlT[q0 + 1][krel] = wv.y;
        wlT[q0 + 2][krel] = wv.z;
        wlT[q0 + 3][krel] = wv.w;
    }
    __syncthreads();

    const int q = t & 15;
    const int b = (t >> 4) & 3;
    const int ks = (t >> 6) * 64;                      // slice start within block
    const int i = (k0 + ks) >> 7;

    const _Float16* p0 = P + (size_t)b * KTOT + k0 + ks;
    const _Float16* p1 = P + (size_t)(BB + b) * KTOT + k0 + ks;

    float acc = 0.f;
#pragma unroll
    for (int seg = 0; seg < 2; ++seg) {
        const int h = ((k0 + ks + seg * 32) >> 5) & 3;
        const float rs = S[((size_t)b * NN + i) * HEADS + h] +
                         S[((size_t)(BB + b) * NN + i) * HEADS + h];
        const float inv = __builtin_amdgcn_rcpf(rs);
#pragma unroll
        for (int k8 = 0; k8 < 4; ++k8) {
            const int kk = seg * 32 + k8 * 8;
            const half8 a0 = *(const half8*)(p0 + kk);
            const half8 a1 = *(const half8*)(p1 + kk);
            const float4 w0 = *(const float4*)&wlT[q][ks + kk];
            const float4 w1 = *(const float4*)&wlT[q][ks + kk + 4];
            acc = fmaf(((float)a0[0] + (float)a1[0]) * inv, w0.x, acc);
            acc = fmaf(((float)a0[1] + (float)a1[1]) * inv, w0.y, acc);
            acc = fmaf(((float)a0[2] + (float)a1[2]) * inv, w0.z, acc);
            acc = fmaf(((float)a0[3] + (float)a1[3]) * inv, w0.w, acc);
            acc = fmaf(((float)a0[4] + (float)a1[4]) * inv, w1.x, acc);
            acc = fmaf(((float)a0[5] + (float)a1[5]) * inv, w1.y, acc);
            acc = fmaf(((float)a0[6] + (float)a1[6]) * inv, w1.z, acc);
            acc = fmaf(((float)a0[7] + (float)a1[7]) * inv, w1.w, acc);
        }
    }

    red[t] = acc;
    __syncthreads();
    if (t < 64)
        atomicAdd(&dout[t], red[t] + red[t + 64] + red[t + 128] + red[t + 192]);
}

extern "C" void kernel_launch(void* const* d_in, const int* in_sizes, int n_in,
                              void* d_out, int out_size, void* d_ws, size_t ws_size,
                              hipStream_t stream)
{
    const float* x       = (const float*)d_in[0];
    const int*   adj     = (const int*)d_in[1];
    const float* W_in    = (const float*)d_in[2];
    const float* b_in    = (const float*)d_in[3];
    const float* att_src = (const float*)d_in[4];
    const float* att_dst = (const float*)d_in[5];
    const float* W_out   = (const float*)d_in[6];
    const float* b_out   = (const float*)d_in[7];
    float* out = (float*)d_out;

    char* ws = (char*)d_ws;
    _Float16* P  = (_Float16*)ws;                                   // 4 MB
    float* S     = (float*)(ws + sizeof(_Float16) * 2 * (size_t)BB * KTOT);   // 256 KB
    float* srcA  = S + 2 * (size_t)BB * NN * HEADS;                 // 128 KB
    float* dstA  = srcA + (size_t)BB * HEADS * NN;                  // 128 KB
    _Float16* hH = (_Float16*)(dstA + (size_t)BB * HEADS * NN);     // 2 MB
    unsigned* adjbw = (unsigned*)((char*)hH + sizeof(_Float16) * (size_t)BB * KTOT); // 512 KB

    k_pre<<<HB + AB, 256, 0, stream>>>(x, W_in, b_in, att_src, att_dst, adj,
                                       hH, srcA, dstA, adjbw, b_out, out);
    k_attn<<<2 * BB * (NN / 32), 512, 0, stream>>>(adjbw, hH, srcA, dstA, P, S);
    k_proj<<<KTOT / 256, 256, 0, stream>>>(P, S, W_out, out);
}